// Round 4
// baseline (693.278 us; speedup 1.0000x reference)
//
#include <hip/hip_runtime.h>

#define N_NODES 20000
#define N_EDGES 200000
#define DIM 128
#define T_STEPS 8
#define N_TILES (N_NODES / 16)   // 1250

typedef short short8 __attribute__((ext_vector_type(8)));
typedef float f32x4 __attribute__((ext_vector_type(4)));

static __device__ __forceinline__ unsigned short f2bf(float f) {
  union { float f; unsigned u; } v; v.f = f;
  unsigned r = v.u + 0x7fffu + ((v.u >> 16) & 1u);   // RNE
  return (unsigned short)(r >> 16);
}

// ---------------------------------------------------------------------------
// Repack the five 128x128 fp32 weight matrices (row-major W[k][n]) into bf16
// MFMA B-fragment order: pack[m][((nt*4+ks)*64+lane)*8+j] = bf16(W[k][n]) with
// n = nt*16 + (lane&15), k = ks*32 + (lane>>4)*8 + j.
// ---------------------------------------------------------------------------
__global__ void repack5(const float* __restrict__ w0,
                        const float* __restrict__ w1,
                        const float* __restrict__ w2,
                        const float* __restrict__ w3,
                        const float* __restrict__ w4,
                        unsigned short* __restrict__ pack) {
  int i = blockIdx.x * blockDim.x + threadIdx.x;
  if (i >= 5 * 16384) return;
  int m = i >> 14, r = i & 16383;
  int j = r & 7, lane = (r >> 3) & 63, ks = (r >> 9) & 3, nt = (r >> 11) & 7;
  int n = nt * 16 + (lane & 15);
  int k = ks * 32 + (lane >> 4) * 8 + j;
  const float* w = (m == 0) ? w0 : (m == 1) ? w1 : (m == 2) ? w2
                 : (m == 3) ? w3 : w4;
  pack[i] = f2bf(w[k * DIM + n]);
}

// ---------------------------------------------------------------------------
// Single-pass scatter over ALL edges into the per-time agg slab:
//   agg[t][dst] += node_emb[src] * rel_emb[type] * w        (fp32 atomics)
// One wave per edge (grid-stride), 2 dims per lane.
// ---------------------------------------------------------------------------
__global__ void scatter_all(const int* __restrict__ src,
                            const int* __restrict__ dst,
                            const int* __restrict__ etype,
                            const int* __restrict__ etime,
                            const float* __restrict__ ew,
                            const float* __restrict__ nemb,
                            const float* __restrict__ remb,
                            float* __restrict__ agg) {
  int lane = threadIdx.x & 63;
  int wid = (blockIdx.x * blockDim.x + threadIdx.x) >> 6;
  int nw = (gridDim.x * blockDim.x) >> 6;
  for (int e = wid; e < N_EDGES; e += nw) {
    int t = etime[e];
    int s = src[e], d = dst[e], rt = etype[e];
    float w = ew[e];
    float2 sv = *((const float2*)(nemb + (size_t)s * DIM) + lane);
    float2 rv = *((const float2*)(remb + (size_t)rt * DIM) + lane);
    float* ap = agg + ((size_t)t * N_NODES + d) * DIM + lane * 2;
    atomicAdd(ap,     sv.x * rv.x * w);
    atomicAdd(ap + 1, sv.y * rv.y * w);
  }
}

// ---------------------------------------------------------------------------
// All-steps encoder: H[t] = tanh(agg[t] @ W_enc), stored in A-fragment order:
//   Hbuf[(((tile*8+t)*4+ks)*64+lane)*8 + j]  (bf16)
// One wave per (tile,t): 10000 waves. MFMA 16x16x32_bf16 layouts (HW-verified):
//   A: m=lane&15, k=quad*8+j;  B: n=lane&15, k=quad*8+j;
//   C/D: col=lane&15, row=quad*4+reg.
// C-layout -> A-layout via LDS (stride 136 => free 2-way bank alias).
// ---------------------------------------------------------------------------
__global__ void enc_all(const float* __restrict__ agg,
                        const unsigned short* __restrict__ pack,
                        unsigned short* __restrict__ Hbuf) {
  __shared__ unsigned short hl[4][16 * 136];
  int lane = threadIdx.x & 63;
  int w = blockIdx.x * (blockDim.x >> 6) + (threadIdx.x >> 6);  // 0..9999
  int t = w & 7, tile = w >> 3;
  int q = lane >> 4, l15 = lane & 15;
  int row0 = tile * 16;

  f32x4 acc[8];
#pragma unroll
  for (int nt = 0; nt < 8; nt++) acc[nt] = (f32x4){0.f, 0.f, 0.f, 0.f};
#pragma unroll
  for (int ks = 0; ks < 4; ks++) {
    const float* ap = agg + ((size_t)t * N_NODES + row0 + l15) * DIM + ks * 32 + q * 8;
    float4 a0 = *(const float4*)ap;
    float4 a1 = *(const float4*)(ap + 4);
    short8 a;
    a[0] = (short)f2bf(a0.x); a[1] = (short)f2bf(a0.y);
    a[2] = (short)f2bf(a0.z); a[3] = (short)f2bf(a0.w);
    a[4] = (short)f2bf(a1.x); a[5] = (short)f2bf(a1.y);
    a[6] = (short)f2bf(a1.z); a[7] = (short)f2bf(a1.w);
#pragma unroll
    for (int nt = 0; nt < 8; nt++) {
      short8 b = *(const short8*)(pack + ((nt * 4 + ks) * 64 + lane) * 8);
      acc[nt] = __builtin_amdgcn_mfma_f32_16x16x32_bf16(a, b, acc[nt], 0, 0, 0);
    }
  }
  unsigned short* h = hl[threadIdx.x >> 6];
#pragma unroll
  for (int nt = 0; nt < 8; nt++)
#pragma unroll
    for (int r = 0; r < 4; r++)
      h[(q * 4 + r) * 136 + nt * 16 + l15] = f2bf(tanhf(acc[nt][r]));
  __syncthreads();   // orders cross-lane LDS write->read
#pragma unroll
  for (int ks = 0; ks < 4; ks++) {
    short8 v = *(const short8*)&h[l15 * 136 + ks * 32 + q * 8];
    *(short8*)(Hbuf + (((size_t)(tile * T_STEPS + t) * 4 + ks) * 64 + lane) * 8) = v;
  }
}

// ---------------------------------------------------------------------------
// Recurrent GRU-cell kernel: one wave per 16-row tile; loops t=0..7 with the
// fp32 state held entirely in registers (C-layout). Per step:
//   state -> bf16 A-frags via LDS round-trip;
//   zpre = H@Wz + S@Uz + bz ; cpre = H@Wh + S@Uh + bh   (128 MFMAs)
//   S = (1-sigmoid(zpre))*S + sigmoid(zpre)*tanh(cpre)
// Final state written to out (fp32).
// ---------------------------------------------------------------------------
__launch_bounds__(64)
__global__ void recur(const unsigned short* __restrict__ Hbuf,
                      const unsigned short* __restrict__ pack,
                      const float* __restrict__ bz,
                      const float* __restrict__ bh,
                      float* __restrict__ out) {
  __shared__ unsigned short sl[16 * 136];
  int lane = threadIdx.x;           // one wave per block
  int tile = blockIdx.x;
  int q = lane >> 4, l15 = lane & 15;

  float bzv[8], bhv[8];
#pragma unroll
  for (int nt = 0; nt < 8; nt++) {
    bzv[nt] = bz[nt * 16 + l15];
    bhv[nt] = bh[nt * 16 + l15];
  }

  f32x4 stC[8];
#pragma unroll
  for (int nt = 0; nt < 8; nt++) stC[nt] = (f32x4){0.f, 0.f, 0.f, 0.f};

  for (int t = 0; t < T_STEPS; t++) {
    // ---- state (C-layout f32 regs) -> bf16 A-frags via LDS ----
#pragma unroll
    for (int nt = 0; nt < 8; nt++)
#pragma unroll
      for (int r = 0; r < 4; r++)
        sl[(q * 4 + r) * 136 + nt * 16 + l15] = f2bf(stC[nt][r]);
    __syncthreads();
    short8 sA[4];
#pragma unroll
    for (int ks = 0; ks < 4; ks++)
      sA[ks] = *(const short8*)&sl[l15 * 136 + ks * 32 + q * 8];
    __syncthreads();   // WAR: reads done before next iteration's writes

    // ---- H A-frags (precomputed layout: coalesced 16B/lane) ----
    short8 hA[4];
#pragma unroll
    for (int ks = 0; ks < 4; ks++)
      hA[ks] = *(const short8*)(Hbuf +
                 (((size_t)(tile * T_STEPS + t) * 4 + ks) * 64 + lane) * 8);

    // ---- gate pre-activations ----
    f32x4 accz[8], accc[8];
#pragma unroll
    for (int nt = 0; nt < 8; nt++) {
      accz[nt] = (f32x4){bzv[nt], bzv[nt], bzv[nt], bzv[nt]};
      accc[nt] = (f32x4){bhv[nt], bhv[nt], bhv[nt], bhv[nt]};
    }
#pragma unroll
    for (int ks = 0; ks < 4; ks++) {
#pragma unroll
      for (int nt = 0; nt < 8; nt++) {
        int fo = ((nt * 4 + ks) * 64 + lane) * 8;
        short8 bwz = *(const short8*)(pack + 16384 * 1 + fo);
        short8 buz = *(const short8*)(pack + 16384 * 2 + fo);
        short8 bwh = *(const short8*)(pack + 16384 * 3 + fo);
        short8 buh = *(const short8*)(pack + 16384 * 4 + fo);
        accz[nt] = __builtin_amdgcn_mfma_f32_16x16x32_bf16(hA[ks], bwz, accz[nt], 0, 0, 0);
        accz[nt] = __builtin_amdgcn_mfma_f32_16x16x32_bf16(sA[ks], buz, accz[nt], 0, 0, 0);
        accc[nt] = __builtin_amdgcn_mfma_f32_16x16x32_bf16(hA[ks], bwh, accc[nt], 0, 0, 0);
        accc[nt] = __builtin_amdgcn_mfma_f32_16x16x32_bf16(sA[ks], buh, accc[nt], 0, 0, 0);
      }
    }

    // ---- GRU update (C-layout, fp32 regs) ----
#pragma unroll
    for (int nt = 0; nt < 8; nt++) {
#pragma unroll
      for (int r = 0; r < 4; r++) {
        float z = 1.f / (1.f + __expf(-accz[nt][r]));
        float c = tanhf(accc[nt][r]);
        stC[nt][r] = (1.f - z) * stC[nt][r] + z * c;
      }
    }
  }

  // ---- final state -> out (fp32) ----
#pragma unroll
  for (int nt = 0; nt < 8; nt++)
#pragma unroll
    for (int r = 0; r < 4; r++)
      out[(size_t)(tile * 16 + q * 4 + r) * DIM + nt * 16 + l15] = stC[nt][r];
}

extern "C" void kernel_launch(void* const* d_in, const int* in_sizes, int n_in,
                              void* d_out, int out_size, void* d_ws, size_t ws_size,
                              hipStream_t stream) {
  const int* eidx  = (const int*)d_in[0];
  const int* src   = eidx;
  const int* dst   = eidx + N_EDGES;
  const int* etype = (const int*)d_in[1];
  const int* etime = (const int*)d_in[2];
  const float* ew   = (const float*)d_in[3];
  const float* nemb = (const float*)d_in[4];
  const float* remb = (const float*)d_in[5];
  const float* Wenc = (const float*)d_in[6];
  const float* Wz   = (const float*)d_in[7];
  const float* Uz   = (const float*)d_in[8];
  const float* Wh   = (const float*)d_in[9];
  const float* Uh   = (const float*)d_in[10];
  const float* bz   = (const float*)d_in[11];
  const float* bh   = (const float*)d_in[12];
  // d_in[13] = num_times (constant 8 for this problem's fixed shapes)

  // ws layout: agg f32 [8*20000*128] (81.92 MB) | Hbuf bf16 (40.96 MB) | pack
  float* agg = (float*)d_ws;
  unsigned short* Hbuf = (unsigned short*)(agg + (size_t)T_STEPS * N_NODES * DIM);
  unsigned short* pack = Hbuf + (size_t)T_STEPS * N_NODES * DIM;
  float* outp = (float*)d_out;

  hipMemsetAsync(agg, 0, (size_t)T_STEPS * N_NODES * DIM * sizeof(float), stream);
  repack5<<<(5 * 16384 + 255) / 256, 256, 0, stream>>>(Wenc, Wz, Uz, Wh, Uh, pack);
  scatter_all<<<1024, 256, 0, stream>>>(src, dst, etype, etime, ew, nemb, remb, agg);
  enc_all<<<(N_TILES * T_STEPS) / 4, 256, 0, stream>>>(agg, pack, Hbuf);
  recur<<<N_TILES, 64, 0, stream>>>(Hbuf, pack, bz, bh, outp);
}

// Round 5
// 383.582 us; speedup vs baseline: 1.8074x; 1.8074x over previous
//
#include <hip/hip_runtime.h>

#define N_NODES 20000
#define N_EDGES 200000
#define DIM 128
#define T_STEPS 8
#define N_TILES (N_NODES / 16)   // 1250

typedef short short8 __attribute__((ext_vector_type(8)));
typedef float f32x4 __attribute__((ext_vector_type(4)));

static __device__ __forceinline__ unsigned short f2bf(float f) {
  union { float f; unsigned u; } v; v.f = f;
  unsigned r = v.u + 0x7fffu + ((v.u >> 16) & 1u);   // RNE
  return (unsigned short)(r >> 16);
}

// ---------------------------------------------------------------------------
// Repack the five 128x128 fp32 weight matrices (row-major W[k][n]) into bf16
// MFMA B-fragment order: pack[m][((nt*4+ks)*64+lane)*8+j] = bf16(W[k][n]) with
// n = nt*16 + (lane&15), k = ks*32 + (lane>>4)*8 + j.
// Slots: 0=Wenc 1=Wz 2=Uz 3=Wh 4=Uh.
// ---------------------------------------------------------------------------
__global__ void repack5(const float* __restrict__ w0,
                        const float* __restrict__ w1,
                        const float* __restrict__ w2,
                        const float* __restrict__ w3,
                        const float* __restrict__ w4,
                        unsigned short* __restrict__ pack) {
  int i = blockIdx.x * blockDim.x + threadIdx.x;
  if (i >= 5 * 16384) return;
  int m = i >> 14, r = i & 16383;
  int j = r & 7, lane = (r >> 3) & 63, ks = (r >> 9) & 3, nt = (r >> 11) & 7;
  int n = nt * 16 + (lane & 15);
  int k = ks * 32 + (lane >> 4) * 8 + j;
  const float* w = (m == 0) ? w0 : (m == 1) ? w1 : (m == 2) ? w2
                 : (m == 3) ? w3 : w4;
  pack[i] = f2bf(w[k * DIM + n]);
}

// ---------------------------------------------------------------------------
// Single-pass scatter over ALL edges into the per-time agg slab:
//   agg[t][dst] += node_emb[src] * rel_emb[type] * w        (fp32 atomics)
// One wave per edge (grid-stride), 2 dims per lane.
// ---------------------------------------------------------------------------
__global__ void scatter_all(const int* __restrict__ src,
                            const int* __restrict__ dst,
                            const int* __restrict__ etype,
                            const int* __restrict__ etime,
                            const float* __restrict__ ew,
                            const float* __restrict__ nemb,
                            const float* __restrict__ remb,
                            float* __restrict__ agg) {
  int lane = threadIdx.x & 63;
  int wid = (blockIdx.x * blockDim.x + threadIdx.x) >> 6;
  int nw = (gridDim.x * blockDim.x) >> 6;
  for (int e = wid; e < N_EDGES; e += nw) {
    int t = etime[e];
    int s = src[e], d = dst[e], rt = etype[e];
    float w = ew[e];
    float2 sv = *((const float2*)(nemb + (size_t)s * DIM) + lane);
    float2 rv = *((const float2*)(remb + (size_t)rt * DIM) + lane);
    float* ap = agg + ((size_t)t * N_NODES + d) * DIM + lane * 2;
    atomicAdd(ap,     sv.x * rv.x * w);
    atomicAdd(ap + 1, sv.y * rv.y * w);
  }
}

// ---------------------------------------------------------------------------
// All-steps encoder + state-independent gate halves. One wave per (tile,t):
//   H    = tanh(agg[t] @ W_enc)           (32 MFMAs)
//   HWz  = H @ Wz + bz ; HWh = H @ Wh + bh  (64 MFMAs)
// HWz/HWh stored fp32 in C-fragment order:
//   HW[((tile*8+t)*8+nt)*256 + lane*4 + r]   (16B/lane coalesced)
// MFMA 16x16x32_bf16 layouts (HW-verified): A: m=lane&15,k=quad*8+j;
// B: n=lane&15,k=quad*8+j;  C/D: col=lane&15, row=quad*4+reg.
// H goes C->A layout via LDS (stride 136 => free 2-way bank alias).
// ---------------------------------------------------------------------------
__global__ void enc_all(const float* __restrict__ agg,
                        const unsigned short* __restrict__ pack,
                        const float* __restrict__ bz,
                        const float* __restrict__ bh,
                        float* __restrict__ HWz,
                        float* __restrict__ HWh) {
  __shared__ unsigned short hl[4][16 * 136];
  int lane = threadIdx.x & 63;
  int w = blockIdx.x * (blockDim.x >> 6) + (threadIdx.x >> 6);  // 0..9999
  int t = w & 7, tile = w >> 3;
  int q = lane >> 4, l15 = lane & 15;
  int row0 = tile * 16;

  // ---- H = tanh(agg @ Wenc) ----
  f32x4 acc[8];
#pragma unroll
  for (int nt = 0; nt < 8; nt++) acc[nt] = (f32x4){0.f, 0.f, 0.f, 0.f};
#pragma unroll
  for (int ks = 0; ks < 4; ks++) {
    const float* ap = agg + ((size_t)t * N_NODES + row0 + l15) * DIM + ks * 32 + q * 8;
    float4 a0 = *(const float4*)ap;
    float4 a1 = *(const float4*)(ap + 4);
    short8 a;
    a[0] = (short)f2bf(a0.x); a[1] = (short)f2bf(a0.y);
    a[2] = (short)f2bf(a0.z); a[3] = (short)f2bf(a0.w);
    a[4] = (short)f2bf(a1.x); a[5] = (short)f2bf(a1.y);
    a[6] = (short)f2bf(a1.z); a[7] = (short)f2bf(a1.w);
#pragma unroll
    for (int nt = 0; nt < 8; nt++) {
      short8 b = *(const short8*)(pack + ((nt * 4 + ks) * 64 + lane) * 8);
      acc[nt] = __builtin_amdgcn_mfma_f32_16x16x32_bf16(a, b, acc[nt], 0, 0, 0);
    }
  }
  unsigned short* h = hl[threadIdx.x >> 6];
#pragma unroll
  for (int nt = 0; nt < 8; nt++)
#pragma unroll
    for (int r = 0; r < 4; r++)
      h[(q * 4 + r) * 136 + nt * 16 + l15] = f2bf(tanhf(acc[nt][r]));
  __syncthreads();   // orders cross-lane LDS write->read
  short8 hA[4];
#pragma unroll
  for (int ks = 0; ks < 4; ks++)
    hA[ks] = *(const short8*)&h[l15 * 136 + ks * 32 + q * 8];

  // ---- HWz = H@Wz + bz ; HWh = H@Wh + bh ----
  f32x4 accz[8], accc[8];
#pragma unroll
  for (int nt = 0; nt < 8; nt++) {
    float vz = bz[nt * 16 + l15];
    float vh = bh[nt * 16 + l15];
    accz[nt] = (f32x4){vz, vz, vz, vz};
    accc[nt] = (f32x4){vh, vh, vh, vh};
  }
#pragma unroll
  for (int ks = 0; ks < 4; ks++) {
#pragma unroll
    for (int nt = 0; nt < 8; nt++) {
      int fo = ((nt * 4 + ks) * 64 + lane) * 8;
      short8 bwz = *(const short8*)(pack + 16384 * 1 + fo);
      short8 bwh = *(const short8*)(pack + 16384 * 3 + fo);
      accz[nt] = __builtin_amdgcn_mfma_f32_16x16x32_bf16(hA[ks], bwz, accz[nt], 0, 0, 0);
      accc[nt] = __builtin_amdgcn_mfma_f32_16x16x32_bf16(hA[ks], bwh, accc[nt], 0, 0, 0);
    }
  }
#pragma unroll
  for (int nt = 0; nt < 8; nt++) {
    size_t o = ((size_t)(tile * T_STEPS + t) * 8 + nt) * 256 + lane * 4;
    *(f32x4*)(HWz + o) = accz[nt];
    *(f32x4*)(HWh + o) = accc[nt];
  }
}

// ---------------------------------------------------------------------------
// Recurrent GRU-cell kernel: 4 waves per block, one block per 16-row tile.
// Wave w owns column-tiles nt = 2w, 2w+1; its Uz/Uh B-fragments stay PINNED
// in registers (16 x short8 = 64 VGPRs) across all 8 steps => no per-step
// weight traffic, no spills. Per step:
//   zpre = HWz[t] + S@Uz ; cpre = HWh[t] + S@Uh   (16 MFMAs per wave)
//   S = (1-sigmoid(zpre))*S + sigmoid(zpre)*tanh(cpre)
// State C-layout regs -> bf16 A-frags via double-buffered LDS, 1 barrier/step
// (safe: __syncthreads drains each wave's own lgkmcnt, and buffers alternate).
// ---------------------------------------------------------------------------
__launch_bounds__(256)
__global__ void recur(const float* __restrict__ HWz,
                      const float* __restrict__ HWh,
                      const unsigned short* __restrict__ pack,
                      float* __restrict__ out) {
  __shared__ unsigned short sl[2][16 * 136];
  int lane = threadIdx.x & 63;
  int wv = threadIdx.x >> 6;        // 0..3
  int tile = blockIdx.x;
  int q = lane >> 4, l15 = lane & 15;

  short8 buz[2][4], buh[2][4];      // pinned Uz/Uh fragments (slots 2 and 4)
#pragma unroll
  for (int ntl = 0; ntl < 2; ntl++) {
    int nt = wv * 2 + ntl;
#pragma unroll
    for (int ks = 0; ks < 4; ks++) {
      int fo = ((nt * 4 + ks) * 64 + lane) * 8;
      buz[ntl][ks] = *(const short8*)(pack + 16384 * 2 + fo);
      buh[ntl][ks] = *(const short8*)(pack + 16384 * 4 + fo);
    }
  }

  f32x4 stC[2];
  stC[0] = (f32x4){0.f, 0.f, 0.f, 0.f};
  stC[1] = (f32x4){0.f, 0.f, 0.f, 0.f};

#pragma unroll
  for (int t = 0; t < T_STEPS; t++) {
    unsigned short* sb = sl[t & 1];
    // state (C-layout f32 regs) -> bf16 A-frag staging
#pragma unroll
    for (int ntl = 0; ntl < 2; ntl++) {
      int nt = wv * 2 + ntl;
#pragma unroll
      for (int r = 0; r < 4; r++)
        sb[(q * 4 + r) * 136 + nt * 16 + l15] = f2bf(stC[ntl][r]);
    }
    __syncthreads();
    short8 sA[4];
#pragma unroll
    for (int ks = 0; ks < 4; ks++)
      sA[ks] = *(const short8*)&sb[l15 * 136 + ks * 32 + q * 8];

    f32x4 accz[2], accc[2];
#pragma unroll
    for (int ntl = 0; ntl < 2; ntl++) {
      int nt = wv * 2 + ntl;
      size_t o = ((size_t)(tile * T_STEPS + t) * 8 + nt) * 256 + lane * 4;
      accz[ntl] = *(const f32x4*)(HWz + o);
      accc[ntl] = *(const f32x4*)(HWh + o);
    }
#pragma unroll
    for (int ks = 0; ks < 4; ks++) {
#pragma unroll
      for (int ntl = 0; ntl < 2; ntl++) {
        accz[ntl] = __builtin_amdgcn_mfma_f32_16x16x32_bf16(sA[ks], buz[ntl][ks], accz[ntl], 0, 0, 0);
        accc[ntl] = __builtin_amdgcn_mfma_f32_16x16x32_bf16(sA[ks], buh[ntl][ks], accc[ntl], 0, 0, 0);
      }
    }
#pragma unroll
    for (int ntl = 0; ntl < 2; ntl++) {
#pragma unroll
      for (int r = 0; r < 4; r++) {
        float z = 1.f / (1.f + __expf(-accz[ntl][r]));
        float c = tanhf(accc[ntl][r]);
        stC[ntl][r] = (1.f - z) * stC[ntl][r] + z * c;
      }
    }
  }

  // final state -> out (fp32)
#pragma unroll
  for (int ntl = 0; ntl < 2; ntl++) {
    int nt = wv * 2 + ntl;
#pragma unroll
    for (int r = 0; r < 4; r++)
      out[(size_t)(tile * 16 + q * 4 + r) * DIM + nt * 16 + l15] = stC[ntl][r];
  }
}

extern "C" void kernel_launch(void* const* d_in, const int* in_sizes, int n_in,
                              void* d_out, int out_size, void* d_ws, size_t ws_size,
                              hipStream_t stream) {
  const int* eidx  = (const int*)d_in[0];
  const int* src   = eidx;
  const int* dst   = eidx + N_EDGES;
  const int* etype = (const int*)d_in[1];
  const int* etime = (const int*)d_in[2];
  const float* ew   = (const float*)d_in[3];
  const float* nemb = (const float*)d_in[4];
  const float* remb = (const float*)d_in[5];
  const float* Wenc = (const float*)d_in[6];
  const float* Wz   = (const float*)d_in[7];
  const float* Uz   = (const float*)d_in[8];
  const float* Wh   = (const float*)d_in[9];
  const float* Uh   = (const float*)d_in[10];
  const float* bz   = (const float*)d_in[11];
  const float* bh   = (const float*)d_in[12];
  // d_in[13] = num_times (constant 8 for this problem's fixed shapes)

  // ws layout: agg f32 (81.92MB) | HWz f32 (81.92MB) | HWh f32 (81.92MB) | pack
  float* agg = (float*)d_ws;
  float* HWz = agg + (size_t)T_STEPS * N_NODES * DIM;
  float* HWh = HWz + (size_t)T_STEPS * N_NODES * DIM;
  unsigned short* pack = (unsigned short*)(HWh + (size_t)T_STEPS * N_NODES * DIM);
  float* outp = (float*)d_out;

  hipMemsetAsync(agg, 0, (size_t)T_STEPS * N_NODES * DIM * sizeof(float), stream);
  repack5<<<(5 * 16384 + 255) / 256, 256, 0, stream>>>(Wenc, Wz, Uz, Wh, Uh, pack);
  scatter_all<<<1024, 256, 0, stream>>>(src, dst, etype, etime, ew, nemb, remb, agg);
  enc_all<<<(N_TILES * T_STEPS) / 4, 256, 0, stream>>>(agg, pack, bz, bh, HWz, HWh);
  recur<<<N_TILES, 256, 0, stream>>>(HWz, HWh, pack, outp);
}

// Round 6
// 264.317 us; speedup vs baseline: 2.6229x; 1.4512x over previous
//
#include <hip/hip_runtime.h>

#define N_NODES 20000
#define N_EDGES 200000
#define DIM 128
#define T_STEPS 8
#define N_TILES (N_NODES / 16)          // 1250
#define NB (T_STEPS * N_NODES)          // 160000 (t,dst) buckets
#define SCAN_N (NB + 1)                 // 160001
#define SCAN_BLKS ((SCAN_N + 1023) / 1024)  // 157

typedef short short8 __attribute__((ext_vector_type(8)));
typedef float f32x4 __attribute__((ext_vector_type(4)));
typedef _Float16 h16x4 __attribute__((ext_vector_type(4)));

static __device__ __forceinline__ unsigned short f2bf(float f) {
  union { float f; unsigned u; } v; v.f = f;
  unsigned r = v.u + 0x7fffu + ((v.u >> 16) & 1u);   // RNE
  return (unsigned short)(r >> 16);
}

// ---------------------------------------------------------------------------
// Repack the five 128x128 fp32 weight matrices (row-major W[k][n]) into bf16
// MFMA B-fragment order. Slots: 0=Wenc 1=Wz 2=Uz 3=Wh 4=Uh.
// ---------------------------------------------------------------------------
__global__ void repack5(const float* __restrict__ w0,
                        const float* __restrict__ w1,
                        const float* __restrict__ w2,
                        const float* __restrict__ w3,
                        const float* __restrict__ w4,
                        unsigned short* __restrict__ pack) {
  int i = blockIdx.x * blockDim.x + threadIdx.x;
  if (i >= 5 * 16384) return;
  int m = i >> 14, r = i & 16383;
  int j = r & 7, lane = (r >> 3) & 63, ks = (r >> 9) & 3, nt = (r >> 11) & 7;
  int n = nt * 16 + (lane & 15);
  int k = ks * 32 + (lane >> 4) * 8 + j;
  const float* w = (m == 0) ? w0 : (m == 1) ? w1 : (m == 2) ? w2
                 : (m == 3) ? w3 : w4;
  pack[i] = f2bf(w[k * DIM + n]);
}

// ------------------------- CSR build (counting sort) -----------------------
__global__ void hist_k(const int* __restrict__ dst,
                       const int* __restrict__ etime,
                       int* __restrict__ counts) {
  int i = blockIdx.x * blockDim.x + threadIdx.x;
  if (i >= N_EDGES) return;
  atomicAdd(&counts[etime[i] * N_NODES + dst[i]], 1);
}

// exclusive scan over counts[0..SCAN_N): 1024 elems/block
__global__ void scan1_k(const int* __restrict__ counts,
                        int* __restrict__ base, int* __restrict__ bsum) {
  __shared__ int ls[256];
  int tid = threadIdx.x;
  int i0 = blockIdx.x * 1024 + tid * 4;
  int v[4], ts = 0;
#pragma unroll
  for (int r = 0; r < 4; r++) {
    v[r] = (i0 + r < SCAN_N) ? counts[i0 + r] : 0;
    ts += v[r];
  }
  ls[tid] = ts; __syncthreads();
#pragma unroll
  for (int off = 1; off < 256; off <<= 1) {
    int x = (tid >= off) ? ls[tid - off] : 0;
    __syncthreads(); ls[tid] += x; __syncthreads();
  }
  int run = ls[tid] - ts;
  if (tid == 255) bsum[blockIdx.x] = ls[255];
#pragma unroll
  for (int r = 0; r < 4; r++) {
    if (i0 + r < SCAN_N) base[i0 + r] = run;
    run += v[r];
  }
}

__global__ void scan2_k(int* __restrict__ bsum) {
  __shared__ int ls[256];
  int tid = threadIdx.x;
  int v = (tid < SCAN_BLKS) ? bsum[tid] : 0;
  ls[tid] = v; __syncthreads();
#pragma unroll
  for (int off = 1; off < 256; off <<= 1) {
    int x = (tid >= off) ? ls[tid - off] : 0;
    __syncthreads(); ls[tid] += x; __syncthreads();
  }
  if (tid < SCAN_BLKS) bsum[tid] = ls[tid] - v;
}

__global__ void scan3_k(int* __restrict__ base, const int* __restrict__ bsum) {
  int i = blockIdx.x * blockDim.x + threadIdx.x;
  if (i < SCAN_N) base[i] += bsum[i >> 10];
}

__global__ void fill_k(const int* __restrict__ src, const int* __restrict__ dst,
                       const int* __restrict__ etype, const int* __restrict__ etime,
                       const float* __restrict__ ew,
                       const int* __restrict__ base, int* __restrict__ cursor,
                       int* __restrict__ ssrc, int* __restrict__ srel,
                       float* __restrict__ sw) {
  int i = blockIdx.x * blockDim.x + threadIdx.x;
  if (i >= N_EDGES) return;
  int key = etime[i] * N_NODES + dst[i];
  int pos = base[key] + atomicAdd(&cursor[key], 1);
  ssrc[pos] = src[i]; srel[pos] = etype[i]; sw[pos] = ew[i];
}

// ---------------------------------------------------------------------------
// Gather: one wave per (t,dst) bucket; fp32 register accumulation, no atomics.
// Writes every agg row exactly once (bf16) -> replaces memset too.
// ---------------------------------------------------------------------------
__global__ void gather_k(const int* __restrict__ base,
                         const int* __restrict__ ssrc,
                         const int* __restrict__ srel,
                         const float* __restrict__ sw,
                         const float* __restrict__ nemb,
                         const float* __restrict__ remb,
                         unsigned short* __restrict__ aggb) {
  int lane = threadIdx.x & 63;
  int b = (blockIdx.x * blockDim.x + threadIdx.x) >> 6;   // 0..NB-1 exactly
  int s0 = base[b], s1 = base[b + 1];
  float ax = 0.f, ay = 0.f;
  for (int i = s0; i < s1; i++) {
    int s = ssrc[i], rt = srel[i];
    float w = sw[i];
    float2 sv = ((const float2*)(nemb + (size_t)s * DIM))[lane];
    float2 rv = ((const float2*)(remb + (size_t)rt * DIM))[lane];
    ax += sv.x * rv.x * w;
    ay += sv.y * rv.y * w;
  }
  ushort2 o; o.x = f2bf(ax); o.y = f2bf(ay);
  ((ushort2*)(aggb + (size_t)b * DIM))[lane] = o;
}

// ---------------------------------------------------------------------------
// All-steps encoder + state-independent gate halves. One wave per (tile,t):
//   H = tanh(agg[t] @ W_enc); HWz = H@Wz + bz; HWh = H@Wh + bh
// agg is bf16 (direct A-frag bits). Preacts stored f16 in C-fragment order:
//   PA[((tile*8+t)*8+nt)*256 + lane*4 + r]   (8B/lane coalesced)
// MFMA 16x16x32_bf16 layouts (HW-verified): A: m=lane&15,k=quad*8+j;
// B: n=lane&15,k=quad*8+j;  C/D: col=lane&15, row=quad*4+reg.
// ---------------------------------------------------------------------------
__global__ void enc_all(const unsigned short* __restrict__ aggb,
                        const unsigned short* __restrict__ pack,
                        const float* __restrict__ bz,
                        const float* __restrict__ bh,
                        _Float16* __restrict__ PAz,
                        _Float16* __restrict__ PAh) {
  __shared__ unsigned short hl[4][16 * 136];
  int lane = threadIdx.x & 63;
  int w = blockIdx.x * (blockDim.x >> 6) + (threadIdx.x >> 6);  // 0..9999
  int t = w & 7, tile = w >> 3;
  int q = lane >> 4, l15 = lane & 15;
  int row0 = tile * 16;

  // ---- H = tanh(agg @ Wenc) ----
  f32x4 acc[8];
#pragma unroll
  for (int nt = 0; nt < 8; nt++) acc[nt] = (f32x4){0.f, 0.f, 0.f, 0.f};
#pragma unroll
  for (int ks = 0; ks < 4; ks++) {
    short8 a = *(const short8*)(aggb +
        ((size_t)t * N_NODES + row0 + l15) * DIM + ks * 32 + q * 8);
#pragma unroll
    for (int nt = 0; nt < 8; nt++) {
      short8 b = *(const short8*)(pack + ((nt * 4 + ks) * 64 + lane) * 8);
      acc[nt] = __builtin_amdgcn_mfma_f32_16x16x32_bf16(a, b, acc[nt], 0, 0, 0);
    }
  }
  unsigned short* h = hl[threadIdx.x >> 6];
#pragma unroll
  for (int nt = 0; nt < 8; nt++)
#pragma unroll
    for (int r = 0; r < 4; r++)
      h[(q * 4 + r) * 136 + nt * 16 + l15] = f2bf(tanhf(acc[nt][r]));
  __syncthreads();   // orders cross-lane LDS write->read
  short8 hA[4];
#pragma unroll
  for (int ks = 0; ks < 4; ks++)
    hA[ks] = *(const short8*)&h[l15 * 136 + ks * 32 + q * 8];

  // ---- HWz = H@Wz + bz ; HWh = H@Wh + bh ----
  f32x4 accz[8], accc[8];
#pragma unroll
  for (int nt = 0; nt < 8; nt++) {
    float vz = bz[nt * 16 + l15];
    float vh = bh[nt * 16 + l15];
    accz[nt] = (f32x4){vz, vz, vz, vz};
    accc[nt] = (f32x4){vh, vh, vh, vh};
  }
#pragma unroll
  for (int ks = 0; ks < 4; ks++) {
#pragma unroll
    for (int nt = 0; nt < 8; nt++) {
      int fo = ((nt * 4 + ks) * 64 + lane) * 8;
      short8 bwz = *(const short8*)(pack + 16384 * 1 + fo);
      short8 bwh = *(const short8*)(pack + 16384 * 3 + fo);
      accz[nt] = __builtin_amdgcn_mfma_f32_16x16x32_bf16(hA[ks], bwz, accz[nt], 0, 0, 0);
      accc[nt] = __builtin_amdgcn_mfma_f32_16x16x32_bf16(hA[ks], bwh, accc[nt], 0, 0, 0);
    }
  }
#pragma unroll
  for (int nt = 0; nt < 8; nt++) {
    size_t o = ((size_t)(tile * T_STEPS + t) * 8 + nt) * 256 + lane * 4;
    h16x4 vz, vh;
#pragma unroll
    for (int r = 0; r < 4; r++) {
      vz[r] = (_Float16)accz[nt][r];
      vh[r] = (_Float16)accc[nt][r];
    }
    *(h16x4*)(PAz + o) = vz;
    *(h16x4*)(PAh + o) = vh;
  }
}

// ---------------------------------------------------------------------------
// Recurrent GRU-cell kernel: 4 waves per block, one block per 16-row tile.
// Wave w owns column-tiles nt = 2w, 2w+1; Uz/Uh B-frags pinned in registers.
//   zpre = PAz[t] + S@Uz ; cpre = PAh[t] + S@Uh   (16 MFMAs/wave/step)
//   S = (1-sigmoid(zpre))*S + sigmoid(zpre)*tanh(cpre)
// ---------------------------------------------------------------------------
__launch_bounds__(256)
__global__ void recur(const _Float16* __restrict__ PAz,
                      const _Float16* __restrict__ PAh,
                      const unsigned short* __restrict__ pack,
                      float* __restrict__ out) {
  __shared__ unsigned short sl[2][16 * 136];
  int lane = threadIdx.x & 63;
  int wv = threadIdx.x >> 6;        // 0..3
  int tile = blockIdx.x;
  int q = lane >> 4, l15 = lane & 15;

  short8 buz[2][4], buh[2][4];      // pinned Uz/Uh fragments (slots 2 and 4)
#pragma unroll
  for (int ntl = 0; ntl < 2; ntl++) {
    int nt = wv * 2 + ntl;
#pragma unroll
    for (int ks = 0; ks < 4; ks++) {
      int fo = ((nt * 4 + ks) * 64 + lane) * 8;
      buz[ntl][ks] = *(const short8*)(pack + 16384 * 2 + fo);
      buh[ntl][ks] = *(const short8*)(pack + 16384 * 4 + fo);
    }
  }

  f32x4 stC[2];
  stC[0] = (f32x4){0.f, 0.f, 0.f, 0.f};
  stC[1] = (f32x4){0.f, 0.f, 0.f, 0.f};

#pragma unroll
  for (int t = 0; t < T_STEPS; t++) {
    unsigned short* sb = sl[t & 1];
    // state (C-layout f32 regs) -> bf16 A-frag staging (double-buffered)
#pragma unroll
    for (int ntl = 0; ntl < 2; ntl++) {
      int nt = wv * 2 + ntl;
#pragma unroll
      for (int r = 0; r < 4; r++)
        sb[(q * 4 + r) * 136 + nt * 16 + l15] = f2bf(stC[ntl][r]);
    }
    __syncthreads();
    short8 sA[4];
#pragma unroll
    for (int ks = 0; ks < 4; ks++)
      sA[ks] = *(const short8*)&sb[l15 * 136 + ks * 32 + q * 8];

    f32x4 accz[2], accc[2];
#pragma unroll
    for (int ntl = 0; ntl < 2; ntl++) {
      int nt = wv * 2 + ntl;
      size_t o = ((size_t)(tile * T_STEPS + t) * 8 + nt) * 256 + lane * 4;
      h16x4 vz = *(const h16x4*)(PAz + o);
      h16x4 vh = *(const h16x4*)(PAh + o);
      accz[ntl] = (f32x4){(float)vz[0], (float)vz[1], (float)vz[2], (float)vz[3]};
      accc[ntl] = (f32x4){(float)vh[0], (float)vh[1], (float)vh[2], (float)vh[3]};
    }
#pragma unroll
    for (int ks = 0; ks < 4; ks++) {
#pragma unroll
      for (int ntl = 0; ntl < 2; ntl++) {
        accz[ntl] = __builtin_amdgcn_mfma_f32_16x16x32_bf16(sA[ks], buz[ntl][ks], accz[ntl], 0, 0, 0);
        accc[ntl] = __builtin_amdgcn_mfma_f32_16x16x32_bf16(sA[ks], buh[ntl][ks], accc[ntl], 0, 0, 0);
      }
    }
#pragma unroll
    for (int ntl = 0; ntl < 2; ntl++) {
#pragma unroll
      for (int r = 0; r < 4; r++) {
        float z = 1.f / (1.f + __expf(-accz[ntl][r]));
        float c = tanhf(accc[ntl][r]);
        stC[ntl][r] = (1.f - z) * stC[ntl][r] + z * c;
      }
    }
  }

  // final state -> out (fp32)
#pragma unroll
  for (int ntl = 0; ntl < 2; ntl++) {
    int nt = wv * 2 + ntl;
#pragma unroll
    for (int r = 0; r < 4; r++)
      out[(size_t)(tile * 16 + q * 4 + r) * DIM + nt * 16 + l15] = stC[ntl][r];
  }
}

extern "C" void kernel_launch(void* const* d_in, const int* in_sizes, int n_in,
                              void* d_out, int out_size, void* d_ws, size_t ws_size,
                              hipStream_t stream) {
  const int* eidx  = (const int*)d_in[0];
  const int* src   = eidx;
  const int* dst   = eidx + N_EDGES;
  const int* etype = (const int*)d_in[1];
  const int* etime = (const int*)d_in[2];
  const float* ew   = (const float*)d_in[3];
  const float* nemb = (const float*)d_in[4];
  const float* remb = (const float*)d_in[5];
  const float* Wenc = (const float*)d_in[6];
  const float* Wz   = (const float*)d_in[7];
  const float* Uz   = (const float*)d_in[8];
  const float* Wh   = (const float*)d_in[9];
  const float* Uh   = (const float*)d_in[10];
  const float* bz   = (const float*)d_in[11];
  const float* bh   = (const float*)d_in[12];
  // d_in[13] = num_times (constant 8 for this problem's fixed shapes)

  // ws layout
  unsigned short* aggb = (unsigned short*)d_ws;               // NB*128 bf16 (41 MB)
  _Float16* PAz = (_Float16*)(aggb + (size_t)NB * DIM);       // 41 MB
  _Float16* PAh = PAz + (size_t)NB * DIM;                     // 41 MB
  int* counts = (int*)(PAh + (size_t)NB * DIM);               // SCAN_N
  int* cursor = counts + SCAN_N;                              // NB
  int* bsum   = cursor + NB;                                  // 256
  int* base   = bsum + 256;                                   // SCAN_N
  int* ssrc   = base + SCAN_N;                                // E
  int* srel   = ssrc + N_EDGES;                               // E
  float* sw   = (float*)(srel + N_EDGES);                     // E
  unsigned short* pack = (unsigned short*)(sw + N_EDGES);     // 5*16384
  float* outp = (float*)d_out;

  hipMemsetAsync(counts, 0, (size_t)(SCAN_N + NB) * sizeof(int), stream);
  repack5<<<(5 * 16384 + 255) / 256, 256, 0, stream>>>(Wenc, Wz, Uz, Wh, Uh, pack);
  hist_k<<<(N_EDGES + 255) / 256, 256, 0, stream>>>(dst, etime, counts);
  scan1_k<<<SCAN_BLKS, 256, 0, stream>>>(counts, base, bsum);
  scan2_k<<<1, 256, 0, stream>>>(bsum);
  scan3_k<<<(SCAN_N + 255) / 256, 256, 0, stream>>>(base, bsum);
  fill_k<<<(N_EDGES + 255) / 256, 256, 0, stream>>>(src, dst, etype, etime, ew,
                                                    base, cursor, ssrc, srel, sw);
  gather_k<<<NB / 4, 256, 0, stream>>>(base, ssrc, srel, sw, nemb, remb, aggb);
  enc_all<<<(N_TILES * T_STEPS) / 4, 256, 0, stream>>>(aggb, pack, bz, bh, PAz, PAh);
  recur<<<N_TILES, 256, 0, stream>>>(PAz, PAh, pack, outp);
}

// Round 7
// 223.112 us; speedup vs baseline: 3.1073x; 1.1847x over previous
//
#include <hip/hip_runtime.h>

#define N_NODES 20000
#define N_EDGES 200000
#define DIM 128
#define T_STEPS 8
#define N_TILES (N_NODES / 16)          // 1250
#define SCAN_N (N_NODES + 1)            // 20001
#define SCAN_BLKS ((SCAN_N + 1023) / 1024)  // 20

typedef short short8 __attribute__((ext_vector_type(8)));
typedef float f32x4 __attribute__((ext_vector_type(4)));

static __device__ __forceinline__ unsigned short f2bf(float f) {
  union { float f; unsigned u; } v; v.f = f;
  unsigned r = v.u + 0x7fffu + ((v.u >> 16) & 1u);   // RNE
  return (unsigned short)(r >> 16);
}
static __device__ __forceinline__ float fast_tanh(float x) {
  float e = __expf(2.f * x);           // inf-safe: x>>0 -> 1, x<<0 -> -1
  return 1.f - 2.f / (e + 1.f);
}
static __device__ __forceinline__ float fast_sig(float x) {
  return 1.f / (1.f + __expf(-x));
}

// ---------------------------------------------------------------------------
// Repack the five 128x128 fp32 weight matrices (row-major W[k][n]) into bf16
// MFMA B-fragment order: pack[m][((nt*4+ks)*64+lane)*8+j] = bf16(W[k][n]),
// n = nt*16 + (lane&15), k = ks*32 + (lane>>4)*8 + j.
// Slots: 0=Wenc 1=Wz 2=Uz 3=Wh 4=Uh.
// ---------------------------------------------------------------------------
__global__ void repack5(const float* __restrict__ w0,
                        const float* __restrict__ w1,
                        const float* __restrict__ w2,
                        const float* __restrict__ w3,
                        const float* __restrict__ w4,
                        unsigned short* __restrict__ pack) {
  int i = blockIdx.x * blockDim.x + threadIdx.x;
  if (i >= 5 * 16384) return;
  int m = i >> 14, r = i & 16383;
  int j = r & 7, lane = (r >> 3) & 63, ks = (r >> 9) & 3, nt = (r >> 11) & 7;
  int n = nt * 16 + (lane & 15);
  int k = ks * 32 + (lane >> 4) * 8 + j;
  const float* w = (m == 0) ? w0 : (m == 1) ? w1 : (m == 2) ? w2
                 : (m == 3) ? w3 : w4;
  pack[i] = f2bf(w[k * DIM + n]);
}

// ------------------------- CSR build: bucket by dst ------------------------
__global__ void hist_k(const int* __restrict__ dst, int* __restrict__ counts) {
  int i = blockIdx.x * blockDim.x + threadIdx.x;
  if (i >= N_EDGES) return;
  atomicAdd(&counts[dst[i]], 1);
}

__global__ void scan1_k(const int* __restrict__ counts,
                        int* __restrict__ base, int* __restrict__ bsum) {
  __shared__ int ls[256];
  int tid = threadIdx.x;
  int i0 = blockIdx.x * 1024 + tid * 4;
  int v[4], ts = 0;
#pragma unroll
  for (int r = 0; r < 4; r++) {
    v[r] = (i0 + r < SCAN_N) ? counts[i0 + r] : 0;
    ts += v[r];
  }
  ls[tid] = ts; __syncthreads();
#pragma unroll
  for (int off = 1; off < 256; off <<= 1) {
    int x = (tid >= off) ? ls[tid - off] : 0;
    __syncthreads(); ls[tid] += x; __syncthreads();
  }
  int run = ls[tid] - ts;
  if (tid == 255) bsum[blockIdx.x] = ls[255];
#pragma unroll
  for (int r = 0; r < 4; r++) {
    if (i0 + r < SCAN_N) base[i0 + r] = run;
    run += v[r];
  }
}

__global__ void scan2_k(int* __restrict__ bsum) {
  __shared__ int ls[256];
  int tid = threadIdx.x;
  int v = (tid < SCAN_BLKS) ? bsum[tid] : 0;
  ls[tid] = v; __syncthreads();
#pragma unroll
  for (int off = 1; off < 256; off <<= 1) {
    int x = (tid >= off) ? ls[tid - off] : 0;
    __syncthreads(); ls[tid] += x; __syncthreads();
  }
  if (tid < SCAN_BLKS) bsum[tid] = ls[tid] - v;
}

__global__ void scan3_k(int* __restrict__ base, const int* __restrict__ bsum) {
  int i = blockIdx.x * blockDim.x + threadIdx.x;
  if (i < SCAN_N) base[i] += bsum[i >> 10];
}

// epack = src | rel<<15 | t<<23  (src<32768, rel<256, t<8)
__global__ void fill_k(const int* __restrict__ src, const int* __restrict__ dst,
                       const int* __restrict__ etype, const int* __restrict__ etime,
                       const float* __restrict__ ew,
                       const int* __restrict__ base, int* __restrict__ cursor,
                       unsigned* __restrict__ epack, float* __restrict__ sw) {
  int i = blockIdx.x * blockDim.x + threadIdx.x;
  if (i >= N_EDGES) return;
  int d = dst[i];
  int pos = base[d] + atomicAdd(&cursor[d], 1);
  epack[pos] = (unsigned)src[i] | ((unsigned)etype[i] << 15) | ((unsigned)etime[i] << 23);
  sw[pos] = ew[i];
}

// ---------------------------------------------------------------------------
// Gather: one wave per dst node; 8 per-t accumulator pairs in registers,
// predicated FMA on wave-uniform t. Writes all 8 agg[t][node] rows (bf16),
// including zeros -> no memset needed.
// ---------------------------------------------------------------------------
__global__ void gather_k(const int* __restrict__ base,
                         const unsigned* __restrict__ epack,
                         const float* __restrict__ sw,
                         const float* __restrict__ nemb,
                         const float* __restrict__ remb,
                         unsigned short* __restrict__ aggb) {
  int lane = threadIdx.x & 63;
  int node = (blockIdx.x * blockDim.x + threadIdx.x) >> 6;   // 0..N_NODES-1
  int s0 = base[node], s1 = base[node + 1];
  float ax[T_STEPS], ay[T_STEPS];
#pragma unroll
  for (int tt = 0; tt < T_STEPS; tt++) { ax[tt] = 0.f; ay[tt] = 0.f; }
  for (int i = s0; i < s1; i++) {
    unsigned u = epack[i];
    float w = sw[i];
    int s = u & 0x7fff, rt = (u >> 15) & 0xff, t = u >> 23;
    float2 sv = ((const float2*)(nemb + (size_t)s * DIM))[lane];
    float2 rv = ((const float2*)(remb + (size_t)rt * DIM))[lane];
    float m0 = sv.x * rv.x * w;
    float m1 = sv.y * rv.y * w;
#pragma unroll
    for (int tt = 0; tt < T_STEPS; tt++) {
      ax[tt] += (t == tt) ? m0 : 0.f;
      ay[tt] += (t == tt) ? m1 : 0.f;
    }
  }
#pragma unroll
  for (int tt = 0; tt < T_STEPS; tt++) {
    ushort2 o; o.x = f2bf(ax[tt]); o.y = f2bf(ay[tt]);
    ((ushort2*)(aggb + ((size_t)tt * N_NODES + node) * DIM))[lane] = o;
  }
}

// ---------------------------------------------------------------------------
// Fully-fused encoder + GRU recurrence. One block per 16-row tile, 8 waves;
// wave wv owns column-tile nt=wv. Pinned B-frags per wave: Wenc,Wz,Uz,Wh,Uh
// for its nt = 20 x short8 = 80 VGPRs. Per step t:
//   aA   = agg[t] A-frags (bf16, shared lines across waves via L1)
//   H    = fast_tanh(agg @ Wenc[:,nt])          (4 MFMAs)
//   H,S -> double-buffered LDS (C-layout, stride 136), ONE barrier,
//   re-read as A-frags (full 128-dim K)
//   zpre = bz + H@Wz + S@Uz ; cpre = bh + H@Wh + S@Uh   (16 MFMAs)
//   S    = (1-sig(zpre))*S + sig(zpre)*fast_tanh(cpre)
// MFMA 16x16x32_bf16 layouts (HW-verified): A: m=lane&15,k=quad*8+j;
// B: n=lane&15,k=quad*8+j;  C/D: col=lane&15, row=quad*4+reg.
// Double-buffer WAR safety: writes of buffer X at step t+2 are ordered after
// barrier(t+1), which is after all reads of X at step t.
// ---------------------------------------------------------------------------
__launch_bounds__(512)
__global__ void fused_recur(const unsigned short* __restrict__ aggb,
                            const unsigned short* __restrict__ pack,
                            const float* __restrict__ bz,
                            const float* __restrict__ bh,
                            float* __restrict__ out) {
  __shared__ unsigned short Hb[2][16 * 136];
  __shared__ unsigned short Sb[2][16 * 136];
  int lane = threadIdx.x & 63;
  int nt = threadIdx.x >> 6;        // wave id = column tile, 0..7
  int tile = blockIdx.x;
  int q = lane >> 4, l15 = lane & 15;
  int row0 = tile * 16;

  // pinned weight B-fragments for this wave's nt
  short8 wenc[4], wz[4], uz[4], wh[4], uh[4];
#pragma unroll
  for (int ks = 0; ks < 4; ks++) {
    int fo = ((nt * 4 + ks) * 64 + lane) * 8;
    wenc[ks] = *(const short8*)(pack + 16384 * 0 + fo);
    wz[ks]   = *(const short8*)(pack + 16384 * 1 + fo);
    uz[ks]   = *(const short8*)(pack + 16384 * 2 + fo);
    wh[ks]   = *(const short8*)(pack + 16384 * 3 + fo);
    uh[ks]   = *(const short8*)(pack + 16384 * 4 + fo);
  }
  float bzv = bz[nt * 16 + l15];
  float bhv = bh[nt * 16 + l15];

  f32x4 stC = (f32x4){0.f, 0.f, 0.f, 0.f};

  for (int t = 0; t < T_STEPS; t++) {
    // ---- encoder for this step: H(:, nt-cols) ----
    f32x4 acch = (f32x4){0.f, 0.f, 0.f, 0.f};
#pragma unroll
    for (int ks = 0; ks < 4; ks++) {
      short8 aA = *(const short8*)(aggb +
          ((size_t)t * N_NODES + row0 + l15) * DIM + ks * 32 + q * 8);
      acch = __builtin_amdgcn_mfma_f32_16x16x32_bf16(aA, wenc[ks], acch, 0, 0, 0);
    }
    unsigned short* hB = Hb[t & 1];
    unsigned short* sB = Sb[t & 1];
#pragma unroll
    for (int r = 0; r < 4; r++) {
      hB[(q * 4 + r) * 136 + nt * 16 + l15] = f2bf(fast_tanh(acch[r]));
      sB[(q * 4 + r) * 136 + nt * 16 + l15] = f2bf(stC[r]);
    }
    __syncthreads();

    short8 hA[4], sA[4];
#pragma unroll
    for (int ks = 0; ks < 4; ks++) {
      hA[ks] = *(const short8*)&hB[l15 * 136 + ks * 32 + q * 8];
      sA[ks] = *(const short8*)&sB[l15 * 136 + ks * 32 + q * 8];
    }

    f32x4 accz = (f32x4){bzv, bzv, bzv, bzv};
    f32x4 accc = (f32x4){bhv, bhv, bhv, bhv};
#pragma unroll
    for (int ks = 0; ks < 4; ks++) {
      accz = __builtin_amdgcn_mfma_f32_16x16x32_bf16(hA[ks], wz[ks], accz, 0, 0, 0);
      accz = __builtin_amdgcn_mfma_f32_16x16x32_bf16(sA[ks], uz[ks], accz, 0, 0, 0);
      accc = __builtin_amdgcn_mfma_f32_16x16x32_bf16(hA[ks], wh[ks], accc, 0, 0, 0);
      accc = __builtin_amdgcn_mfma_f32_16x16x32_bf16(sA[ks], uh[ks], accc, 0, 0, 0);
    }
#pragma unroll
    for (int r = 0; r < 4; r++) {
      float z = fast_sig(accz[r]);
      float c = fast_tanh(accc[r]);
      stC[r] = (1.f - z) * stC[r] + z * c;
    }
  }

  // final state -> out (fp32, C-layout positions)
#pragma unroll
  for (int r = 0; r < 4; r++)
    out[(size_t)(row0 + q * 4 + r) * DIM + nt * 16 + l15] = stC[r];
}

extern "C" void kernel_launch(void* const* d_in, const int* in_sizes, int n_in,
                              void* d_out, int out_size, void* d_ws, size_t ws_size,
                              hipStream_t stream) {
  const int* eidx  = (const int*)d_in[0];
  const int* src   = eidx;
  const int* dst   = eidx + N_EDGES;
  const int* etype = (const int*)d_in[1];
  const int* etime = (const int*)d_in[2];
  const float* ew   = (const float*)d_in[3];
  const float* nemb = (const float*)d_in[4];
  const float* remb = (const float*)d_in[5];
  const float* Wenc = (const float*)d_in[6];
  const float* Wz   = (const float*)d_in[7];
  const float* Uz   = (const float*)d_in[8];
  const float* Wh   = (const float*)d_in[9];
  const float* Uh   = (const float*)d_in[10];
  const float* bz   = (const float*)d_in[11];
  const float* bh   = (const float*)d_in[12];
  // d_in[13] = num_times (constant 8 for this problem's fixed shapes)

  // ws layout
  unsigned short* aggb = (unsigned short*)d_ws;                    // 8*20000*128 bf16 (41 MB)
  int* counts = (int*)(aggb + (size_t)T_STEPS * N_NODES * DIM);    // SCAN_N
  int* cursor = counts + SCAN_N;                                   // N_NODES
  int* bsum   = cursor + N_NODES;                                  // 64
  int* base   = bsum + 64;                                         // SCAN_N
  unsigned* epack = (unsigned*)(base + SCAN_N);                    // E
  float* sw   = (float*)(epack + N_EDGES);                         // E
  unsigned short* pack = (unsigned short*)(sw + N_EDGES);          // 5*16384
  float* outp = (float*)d_out;

  hipMemsetAsync(counts, 0, (size_t)(SCAN_N + N_NODES) * sizeof(int), stream);
  repack5<<<(5 * 16384 + 255) / 256, 256, 0, stream>>>(Wenc, Wz, Uz, Wh, Uh, pack);
  hist_k<<<(N_EDGES + 255) / 256, 256, 0, stream>>>(dst, counts);
  scan1_k<<<SCAN_BLKS, 256, 0, stream>>>(counts, base, bsum);
  scan2_k<<<1, 256, 0, stream>>>(bsum);
  scan3_k<<<(SCAN_N + 255) / 256, 256, 0, stream>>>(base, bsum);
  fill_k<<<(N_EDGES + 255) / 256, 256, 0, stream>>>(src, dst, etype, etime, ew,
                                                    base, cursor, epack, sw);
  gather_k<<<N_NODES / 4, 256, 0, stream>>>(base, epack, sw, nemb, remb, aggb);
  fused_recur<<<N_TILES, 512, 0, stream>>>(aggb, pack, bz, bh, outp);
}